// Round 7
// baseline (366.228 us; speedup 1.0000x reference)
//
#include <hip/hip_runtime.h>
#include <math.h>

// ---------------------------------------------------------------------------
// GCN critic network. v7: dual-node interleaved gather (2x MLP per wave).
// Round-6 counters: FETCH halved (fp16) but time flat; nothing saturated
// (VALU 13%, HBM 5.5%) -> latency-bound gather. Fix: 2 nodes per wave with
// interleaved 8-deep pipelines (16 gathers in flight), int4-batched index
// loads (10 VMEM/batch instead of 16), and layer-3 agg un-fused from pooling
// (the fused grid-stride serial chain was the round-3 regression).
//   zero -> hist -> scanA/B/(scanC+dinv) -> fill(src only)
//   -> [mm*dinv -> agg]x3 -> pool -> head
// ---------------------------------------------------------------------------

typedef _Float16 half8 __attribute__((ext_vector_type(8)));

__global__ __launch_bounds__(256) void zero_kernel(int* __restrict__ degc,
                                                   float* __restrict__ psum,
                                                   unsigned int* __restrict__ pmax, int n) {
  int i = blockIdx.x * 256 + threadIdx.x;
  if (i < n) degc[i] = 0;
  if (blockIdx.x == 0 && threadIdx.x < 64) {
    psum[threadIdx.x] = 0.0f;
    pmax[threadIdx.x] = 0u;
  }
}

__global__ __launch_bounds__(256) void hist_kernel(const int* __restrict__ dst,
                                                   int* __restrict__ degc, int E) {
  int e = blockIdx.x * 256 + threadIdx.x;
  if (e < E) atomicAdd(&degc[dst[e]], 1);
}

// --- hierarchical exclusive scan of degc -> rowptr (and cursor copy) --------
__global__ __launch_bounds__(256) void scanA_kernel(const int* __restrict__ deg,
                                                    int* __restrict__ bsum, int n) {
  __shared__ int sdata[256];
  int t = threadIdx.x;
  int i = blockIdx.x * 256 + t;
  sdata[t] = (i < n) ? deg[i] : 0;
  __syncthreads();
  for (int off = 128; off > 0; off >>= 1) {
    if (t < off) sdata[t] += sdata[t + off];
    __syncthreads();
  }
  if (t == 0) bsum[blockIdx.x] = sdata[0];
}

__global__ __launch_bounds__(256) void scanB_kernel(int* __restrict__ bsum, int nb) {
  __shared__ int s[256];
  int t = threadIdx.x;
  int v = (t < nb) ? bsum[t] : 0;
  s[t] = v;
  __syncthreads();
  for (int off = 1; off < 256; off <<= 1) {
    int x = (t >= off) ? s[t - off] : 0;
    __syncthreads();
    s[t] += x;
    __syncthreads();
  }
  if (t < nb) bsum[t] = s[t] - v;  // exclusive block offsets
}

// scanC also computes dinv = rsqrt(deg+1)
__global__ __launch_bounds__(256) void scanC_kernel(const int* __restrict__ deg,
                                                    const int* __restrict__ bsum,
                                                    int* __restrict__ rowptr,
                                                    int* __restrict__ cursor,
                                                    float* __restrict__ dinv,
                                                    int n, int e_total) {
  __shared__ int s[256];
  int t = threadIdx.x;
  int i = blockIdx.x * 256 + t;
  int v = (i < n) ? deg[i] : 0;
  s[t] = v;
  __syncthreads();
  for (int off = 1; off < 256; off <<= 1) {
    int x = (t >= off) ? s[t - off] : 0;
    __syncthreads();
    s[t] += x;
    __syncthreads();
  }
  if (i < n) {
    int excl = bsum[blockIdx.x] + s[t] - v;
    rowptr[i] = excl;
    cursor[i] = excl;
    dinv[i] = 1.0f / sqrtf((float)v + 1.0f);
  }
  if (i == 0) rowptr[n] = e_total;
}

__global__ __launch_bounds__(256) void fill_kernel(const int* __restrict__ src,
                                                   const int* __restrict__ dst,
                                                   int* __restrict__ cursor,
                                                   int* __restrict__ csr_src, int E) {
  int e = blockIdx.x * 256 + threadIdx.x;
  if (e >= E) return;
  int s = src[e], d = dst[e];
  int pos = atomicAdd(&cursor[d], 1);
  csr_src[pos] = s;
}

// --- dense matmul C[N,64] = fp16( dinv[row] * (A[N,K] @ W[K,64]) ) ----------
template <int K>
__global__ __launch_bounds__(256) void mm_kernel(const float* __restrict__ A,
                                                 const float* __restrict__ W,
                                                 const float* __restrict__ dinv,
                                                 _Float16* __restrict__ C, int nrows) {
  __shared__ float As[64 * K];
  const int t = threadIdx.x;
  const int lane = t & 63;
  const int wid = __builtin_amdgcn_readfirstlane(t >> 6);
  const int row0 = blockIdx.x * 64;

  constexpr int F4_PER_ROW = K / 4;
  constexpr int ROW_SHIFT = (K == 128) ? 5 : 4;  // log2(F4_PER_ROW)
#pragma unroll
  for (int i = 0; i < K / 16; ++i) {  // 256 threads x K/16 float4 = 64*K floats
    int e4 = t + 256 * i;
    int r = e4 >> ROW_SHIFT;
    int k = (e4 & (F4_PER_ROW - 1)) * 4;
    int rc = row0 + r;
    if (rc > nrows - 1) rc = nrows - 1;  // clamp: duplicate rows never stored
    float4 v = *(const float4*)(A + (size_t)rc * K + k);
    int s = r & 31;
    As[r * K + ((k + 0) ^ s)] = v.x;
    As[r * K + ((k + 1) ^ s)] = v.y;
    As[r * K + ((k + 2) ^ s)] = v.z;
    As[r * K + ((k + 3) ^ s)] = v.w;
  }
  __syncthreads();

  const int colbase = wid * 16;
  const float* Wc = W + colbase;
  float acc[16];
#pragma unroll
  for (int j = 0; j < 16; ++j) acc[j] = 0.0f;
  const int sw = lane & 31;
  const float* Arow = As + lane * K;

#pragma unroll 8
  for (int k = 0; k < K; ++k) {
    float a = Arow[k ^ sw];            // ds_read_b32, conflict-free
    const float* Wk = Wc + k * 64;     // wave-uniform -> s_load
#pragma unroll
    for (int j = 0; j < 16; ++j) acc[j] = fmaf(a, Wk[j], acc[j]);
  }

  int row = row0 + lane;
  if (row < nrows) {
    float dv = dinv[row];
    _Float16* Crow = C + (size_t)row * 64 + colbase;
    half8 o0, o1;
#pragma unroll
    for (int q = 0; q < 8; ++q) o0[q] = (_Float16)(dv * acc[q]);      // RTN
#pragma unroll
    for (int q = 0; q < 8; ++q) o1[q] = (_Float16)(dv * acc[8 + q]);  // RTN
    *(half8*)(Crow + 0) = o0;
    *(half8*)(Crow + 8) = o1;
  }
}

// load 8 consecutive ints as two int4 (dwordx4-capable; 4B-aligned is legal)
__device__ __forceinline__ void ld8(const int* __restrict__ p, int4& a, int4& b) {
  __builtin_memcpy(&a, p, 16);
  __builtin_memcpy(&b, p + 4, 16);
}

// single-node 8-deep pipelined gather (tail path)
__device__ __forceinline__ float gather1(const _Float16* __restrict__ hp,
                                         const int* __restrict__ csr,
                                         int j, int end, int lane, float acc) {
  int c = end - j;
  if (c >= 8) {
    int4 ia, ib;
    ld8(csr + j, ia, ib);
    bool more;
    do {
      j += 8;
      c -= 8;
      float v0 = (float)hp[(ia.x << 6) + lane];
      float v1 = (float)hp[(ia.y << 6) + lane];
      float v2 = (float)hp[(ia.z << 6) + lane];
      float v3 = (float)hp[(ia.w << 6) + lane];
      float v4 = (float)hp[(ib.x << 6) + lane];
      float v5 = (float)hp[(ib.y << 6) + lane];
      float v6 = (float)hp[(ib.z << 6) + lane];
      float v7 = (float)hp[(ib.w << 6) + lane];
      more = (c >= 8);
      int jp = more ? j : j - 8;  // always-valid prefetch address
      int4 ta, tb;
      ld8(csr + jp, ta, tb);
      acc += ((v0 + v1) + (v2 + v3)) + ((v4 + v5) + (v6 + v7));
      ia = ta;
      ib = tb;
    } while (more);
  }
  for (; c > 0; --c, ++j) acc += (float)hp[(csr[j] << 6) + lane];
  return acc;
}

// dual-node interleaved gather: two independent 8-deep chains -> 16 row
// gathers + 4 idx vectors in flight per wave.
__device__ __forceinline__ void gather2(const _Float16* __restrict__ hp,
                                        const int* __restrict__ csr,
                                        int j0, int e0, int j1, int e1, int lane,
                                        float& A0, float& A1) {
  float acc0 = A0, acc1 = A1;
  int c0 = e0 - j0, c1 = e1 - j1;
  if (c0 >= 8 && c1 >= 8) {
    int4 a0, a1, b0, b1;
    ld8(csr + j0, a0, a1);
    ld8(csr + j1, b0, b1);
    bool more;
    do {
      j0 += 8; c0 -= 8;
      j1 += 8; c1 -= 8;
      float u0 = (float)hp[(a0.x << 6) + lane];
      float u1 = (float)hp[(a0.y << 6) + lane];
      float u2 = (float)hp[(a0.z << 6) + lane];
      float u3 = (float)hp[(a0.w << 6) + lane];
      float u4 = (float)hp[(a1.x << 6) + lane];
      float u5 = (float)hp[(a1.y << 6) + lane];
      float u6 = (float)hp[(a1.z << 6) + lane];
      float u7 = (float)hp[(a1.w << 6) + lane];
      float v0 = (float)hp[(b0.x << 6) + lane];
      float v1 = (float)hp[(b0.y << 6) + lane];
      float v2 = (float)hp[(b0.z << 6) + lane];
      float v3 = (float)hp[(b0.w << 6) + lane];
      float v4 = (float)hp[(b1.x << 6) + lane];
      float v5 = (float)hp[(b1.y << 6) + lane];
      float v6 = (float)hp[(b1.z << 6) + lane];
      float v7 = (float)hp[(b1.w << 6) + lane];
      more = (c0 >= 8) && (c1 >= 8);
      int jp0 = more ? j0 : j0 - 8;
      int jp1 = more ? j1 : j1 - 8;
      int4 ta0, ta1, tb0, tb1;
      ld8(csr + jp0, ta0, ta1);
      ld8(csr + jp1, tb0, tb1);
      acc0 += ((u0 + u1) + (u2 + u3)) + ((u4 + u5) + (u6 + u7));
      acc1 += ((v0 + v1) + (v2 + v3)) + ((v4 + v5) + (v6 + v7));
      a0 = ta0; a1 = ta1; b0 = tb0; b1 = tb1;
    } while (more);
  }
  A0 = gather1(hp, csr, j0, e0, lane, acc0);
  A1 = gather1(hp, csr, j1, e1, lane, acc1);
}

// --- CSR pull aggregation, 2 nodes per wave ---------------------------------
__global__ __launch_bounds__(256) void agg_kernel(const _Float16* __restrict__ hp,
                                                  const int* __restrict__ rowptr,
                                                  const int* __restrict__ csr_src,
                                                  const float* __restrict__ dinv,
                                                  const float* __restrict__ bias,
                                                  float* __restrict__ out, int n) {
  const int lane = threadIdx.x & 63;
  const int wid = __builtin_amdgcn_readfirstlane(threadIdx.x >> 6);
  const int node0 = (blockIdx.x * 4 + wid) * 2;
  if (node0 >= n) return;
  const int node1 = node0 + 1;
  const float bl = bias[lane];
  int r0 = rowptr[node0];
  int r1 = rowptr[node0 + 1];
  float acc0 = (float)hp[(node0 << 6) + lane];  // self (already dinv-scaled)
  if (node1 < n) {
    int r2 = rowptr[node1 + 1];
    float acc1 = (float)hp[(node1 << 6) + lane];
    gather2(hp, csr_src, r0, r1, r1, r2, lane, acc0, acc1);
    out[(node0 << 6) + lane] = fmaxf(fmaf(dinv[node0], acc0, bl), 0.0f);
    out[(node1 << 6) + lane] = fmaxf(fmaf(dinv[node1], acc1, bl), 0.0f);
  } else {
    acc0 = gather1(hp, csr_src, r0, r1, lane, acc0);
    out[(node0 << 6) + lane] = fmaxf(fmaf(dinv[node0], acc0, bl), 0.0f);
  }
}

// --- pooling: per-feature sum and max over all nodes (fp32 input) -----------
__global__ __launch_bounds__(256) void pool_kernel(const float* __restrict__ g,
                                                   float* __restrict__ psum,
                                                   unsigned int* __restrict__ pmax, int n) {
  __shared__ float ls[4][64];
  __shared__ float lm[4][64];
  int lane = threadIdx.x & 63;
  int wid = threadIdx.x >> 6;
  float s = 0.0f, m = 0.0f;  // post-relu values >= 0, so 0 is identity for max
  for (int node = blockIdx.x * 4 + wid; node < n; node += gridDim.x * 4) {
    float v = g[(node << 6) + lane];
    s += v;
    m = fmaxf(m, v);
  }
  ls[wid][lane] = s;
  lm[wid][lane] = m;
  __syncthreads();
  if (wid == 0) {
    for (int w = 1; w < 4; ++w) {
      s += ls[w][lane];
      m = fmaxf(m, lm[w][lane]);
    }
    atomicAdd(&psum[lane], s);
    atomicMax(&pmax[lane], __float_as_uint(m));  // valid: m >= 0
  }
}

// --- MLP head: [1,128] -> relu fc1 [128,64] -> fc2 [64,1] -------------------
__global__ __launch_bounds__(64) void head_kernel(const float* __restrict__ psum,
                                                  const float* __restrict__ pmaxf,
                                                  const float* __restrict__ fw1,
                                                  const float* __restrict__ fb1,
                                                  const float* __restrict__ fw2,
                                                  const float* __restrict__ fb2,
                                                  float* __restrict__ out, float invN) {
  int lane = threadIdx.x;
  float acc = fb1[lane];
#pragma unroll 4
  for (int k = 0; k < 64; ++k)
    acc = fmaf(psum[k] * invN, fw1[k * 64 + lane], acc);
#pragma unroll 4
  for (int k = 0; k < 64; ++k)
    acc = fmaf(pmaxf[k], fw1[(64 + k) * 64 + lane], acc);
  float a = fmaxf(acc, 0.0f) * fw2[lane];
  for (int off = 32; off > 0; off >>= 1) a += __shfl_down(a, off);
  if (lane == 0) out[0] = a + fb2[0];
}

extern "C" void kernel_launch(void* const* d_in, const int* in_sizes, int n_in,
                              void* d_out, int out_size, void* d_ws, size_t ws_size,
                              hipStream_t stream) {
  const float* x   = (const float*)d_in[0];
  const int*   ei  = (const int*)d_in[1];
  const float* W1  = (const float*)d_in[2];
  const float* b1  = (const float*)d_in[3];
  const float* W2  = (const float*)d_in[4];
  const float* b2  = (const float*)d_in[5];
  const float* W3  = (const float*)d_in[6];
  const float* b3  = (const float*)d_in[7];
  const float* fw1 = (const float*)d_in[8];
  const float* fb1 = (const float*)d_in[9];
  const float* fw2 = (const float*)d_in[10];
  const float* fb2 = (const float*)d_in[11];
  float* out = (float*)d_out;

  const int N = in_sizes[0] / 128;  // 50000
  const int E = in_sizes[1] / 2;    // 800000
  const int* src = ei;
  const int* dst = ei + E;

  // workspace carve-up (256B aligned slices)
  char* ws = (char*)d_ws;
  size_t off = 0;
  auto alloc = [&](size_t bytes) -> char* {
    char* p = ws + off;
    off = (off + bytes + 255) & ~(size_t)255;
    return p;
  };
  float*        dinv    = (float*)alloc((size_t)N * 4);
  int*          degc    = (int*)alloc((size_t)N * 4);
  int*          rowptr  = (int*)alloc((size_t)(N + 1) * 4);
  int*          cursor  = (int*)alloc((size_t)N * 4);
  int*          bsum    = (int*)alloc(256 * 4);
  int*          csr_src = (int*)alloc((size_t)E * 4 + 64);  // +64: safe int4 overread
  _Float16*     bufA    = (_Float16*)alloc((size_t)N * 64 * 2);  // fp16 h'
  float*        bufB    = (float*)alloc((size_t)N * 64 * 4);     // fp32 agg out
  float*        psum    = (float*)alloc(64 * 4);
  unsigned int* pmax    = (unsigned int*)alloc(64 * 4);

  const int histBlk = (E + 255) / 256;
  const int scanBlk = (N + 255) / 256;  // 196 (<= 256, required by scanB)
  const int mmBlk   = (N + 63) / 64;
  const int aggBlk  = (N / 2 + 3) / 4;  // 2 nodes per wave, 4 waves per block

  zero_kernel<<<scanBlk, 256, 0, stream>>>(degc, psum, pmax, N);
  hist_kernel<<<histBlk, 256, 0, stream>>>(dst, degc, E);
  scanA_kernel<<<scanBlk, 256, 0, stream>>>(degc, bsum, N);
  scanB_kernel<<<1, 256, 0, stream>>>(bsum, scanBlk);
  scanC_kernel<<<scanBlk, 256, 0, stream>>>(degc, bsum, rowptr, cursor, dinv, N, E);
  fill_kernel<<<histBlk, 256, 0, stream>>>(src, dst, cursor, csr_src, E);

  // layer 1: h' = fp16(dinv .* (x @ W1)) -> bufA; aggregate+relu -> bufB (fp32)
  mm_kernel<128><<<mmBlk, 256, 0, stream>>>(x, W1, dinv, bufA, N);
  agg_kernel<<<aggBlk, 256, 0, stream>>>(bufA, rowptr, csr_src, dinv, b1, bufB, N);
  // layer 2
  mm_kernel<64><<<mmBlk, 256, 0, stream>>>(bufB, W2, dinv, bufA, N);
  agg_kernel<<<aggBlk, 256, 0, stream>>>(bufA, rowptr, csr_src, dinv, b2, bufB, N);
  // layer 3 (un-fused: agg -> bufB, then streaming pool)
  mm_kernel<64><<<mmBlk, 256, 0, stream>>>(bufB, W3, dinv, bufA, N);
  agg_kernel<<<aggBlk, 256, 0, stream>>>(bufA, rowptr, csr_src, dinv, b3, bufB, N);

  pool_kernel<<<2048, 256, 0, stream>>>(bufB, psum, pmax, N);
  head_kernel<<<1, 64, 0, stream>>>(psum, (const float*)pmax, fw1, fb1, fw2, fb2, out,
                                    1.0f / (float)N);
}

// Round 8
// 336.212 us; speedup vs baseline: 1.0893x; 1.0893x over previous
//
#include <hip/hip_runtime.h>
#include <math.h>

// ---------------------------------------------------------------------------
// GCN critic network. v8.
// agg: 4 edges per gather wave-instruction (lane g=l>>4 reads 8B of edge g's
//   fp16 row at feature quad s=l&15), indices via scalar s_load (node is
//   readfirstlane-uniform), shfl_xor butterfly epilogue. Rationale: r3-r7
//   showed agg time ~ gather-instr count x 64 divergent addrs (bytes/lines/
//   in-flight depth all null) -> cut address work ~3-4x.
// fill -> two-pass binning (binA: bucket by dst>>8 with LDS reorder +
//   coalesced run writes; binB: per-bucket CSR build, scattered writes
//   confined to one block's 16KB window = single-XCD L2 write combining).
//   Replaces the 53MB-write / 58us fill (8-XCD false sharing).
// ---------------------------------------------------------------------------

typedef _Float16 h4 __attribute__((ext_vector_type(4)));
typedef _Float16 half8 __attribute__((ext_vector_type(8)));

__global__ __launch_bounds__(256) void zero_kernel(int* __restrict__ degc,
                                                   float* __restrict__ psum,
                                                   unsigned int* __restrict__ pmax, int n) {
  int i = blockIdx.x * 256 + threadIdx.x;
  if (i < n) degc[i] = 0;
  if (blockIdx.x == 0 && threadIdx.x < 64) {
    psum[threadIdx.x] = 0.0f;
    pmax[threadIdx.x] = 0u;
  }
}

__global__ __launch_bounds__(256) void hist_kernel(const int* __restrict__ dst,
                                                   int* __restrict__ degc, int E) {
  int e = blockIdx.x * 256 + threadIdx.x;
  if (e < E) atomicAdd(&degc[dst[e]], 1);
}

// --- hierarchical exclusive scan of degc -> rowptr --------------------------
__global__ __launch_bounds__(256) void scanA_kernel(const int* __restrict__ deg,
                                                    int* __restrict__ bsum, int n) {
  __shared__ int sdata[256];
  int t = threadIdx.x;
  int i = blockIdx.x * 256 + t;
  sdata[t] = (i < n) ? deg[i] : 0;
  __syncthreads();
  for (int off = 128; off > 0; off >>= 1) {
    if (t < off) sdata[t] += sdata[t + off];
    __syncthreads();
  }
  if (t == 0) bsum[blockIdx.x] = sdata[0];
}

__global__ __launch_bounds__(256) void scanB_kernel(int* __restrict__ bsum, int nb) {
  __shared__ int s[256];
  int t = threadIdx.x;
  int v = (t < nb) ? bsum[t] : 0;
  s[t] = v;
  __syncthreads();
  for (int off = 1; off < 256; off <<= 1) {
    int x = (t >= off) ? s[t - off] : 0;
    __syncthreads();
    s[t] += x;
    __syncthreads();
  }
  if (t < nb) bsum[t] = s[t] - v;  // exclusive block offsets
}

// scanC: rowptr + dinv + per-bucket write cursors (bucket = node>>8)
__global__ __launch_bounds__(256) void scanC_kernel(const int* __restrict__ deg,
                                                    const int* __restrict__ bsum,
                                                    int* __restrict__ rowptr,
                                                    float* __restrict__ dinv,
                                                    int* __restrict__ bkt_cur,
                                                    int n, int e_total) {
  __shared__ int s[256];
  int t = threadIdx.x;
  int i = blockIdx.x * 256 + t;
  int v = (i < n) ? deg[i] : 0;
  s[t] = v;
  __syncthreads();
  for (int off = 1; off < 256; off <<= 1) {
    int x = (t >= off) ? s[t - off] : 0;
    __syncthreads();
    s[t] += x;
    __syncthreads();
  }
  if (i < n) {
    int excl = bsum[blockIdx.x] + s[t] - v;
    rowptr[i] = excl;
    dinv[i] = 1.0f / sqrtf((float)v + 1.0f);
    if ((i & 255) == 0) bkt_cur[i >> 8] = excl;  // bucket base in CSR coords
  }
  if (i == 0) rowptr[n] = e_total;
}

// --- binA: bucket-sort edges by dst>>8, packed (src<<8)|(dst&255) -----------
__global__ __launch_bounds__(256) void binA_kernel(const int* __restrict__ src,
                                                   const int* __restrict__ dst,
                                                   int* __restrict__ bkt_cur,
                                                   int* __restrict__ binned, int E) {
  __shared__ int hist[256];
  __shared__ int scan[256];
  __shared__ int delta[256];
  __shared__ int lcur[256];
  __shared__ int sorted[4096];
  __shared__ unsigned char bkt_of[4096];
  const int t = threadIdx.x;
  hist[t] = 0;
  __syncthreads();
  const int e0 = blockIdx.x * 4096;
  int pk[16];
  int bk[16];
#pragma unroll
  for (int i = 0; i < 16; ++i) {
    int e = e0 + t + 256 * i;  // coalesced
    if (e < E) {
      int s_ = src[e], d_ = dst[e];
      int b = d_ >> 8;
      pk[i] = (s_ << 8) | (d_ & 255);
      bk[i] = b;
      atomicAdd(&hist[b], 1);
    } else {
      bk[i] = -1;
    }
  }
  __syncthreads();
  int v = hist[t];
  scan[t] = v;
  __syncthreads();
  for (int off = 1; off < 256; off <<= 1) {
    int x = (t >= off) ? scan[t - off] : 0;
    __syncthreads();
    scan[t] += x;
    __syncthreads();
  }
  int excl = scan[t] - v;
  int g = (v > 0) ? atomicAdd(&bkt_cur[t], v) : 0;  // reserve global space
  delta[t] = g - excl;
  lcur[t] = excl;
  __syncthreads();
#pragma unroll
  for (int i = 0; i < 16; ++i) {
    if (bk[i] >= 0) {
      int p = atomicAdd(&lcur[bk[i]], 1);
      sorted[p] = pk[i];
      bkt_of[p] = (unsigned char)bk[i];
    }
  }
  __syncthreads();
  const int tot = scan[255];
  for (int i = t; i < tot; i += 256)  // coalesced run writes
    binned[delta[bkt_of[i]] + i] = sorted[i];
}

// --- binB: per-bucket CSR build (one block per 256-node bucket) -------------
__global__ __launch_bounds__(256) void binB_kernel(const int* __restrict__ rowptr,
                                                   const int* __restrict__ binned,
                                                   int* __restrict__ csr_src, int n) {
  __shared__ int lcur[256];
  const int t = threadIdx.x;
  const int base = blockIdx.x << 8;
  const int rbeg = rowptr[base];
  const int node = base + t;
  lcur[t] = (node < n) ? rowptr[node] - rbeg : 0;
  const int nend = (base + 256 < n) ? base + 256 : n;
  const int rend = rowptr[nend];
  const int cnt = rend - rbeg;
  __syncthreads();
  for (int i = t; i < cnt; i += 256) {
    int e = binned[rbeg + i];               // coalesced read
    int p = atomicAdd(&lcur[e & 255], 1);   // LDS cursor
    csr_src[rbeg + p] = e >> 8;             // scatter within 16KB window
  }
}

// --- dense matmul C[N,64] = fp16( dinv[row] * (A[N,K] @ W[K,64]) ) ----------
template <int K>
__global__ __launch_bounds__(256) void mm_kernel(const float* __restrict__ A,
                                                 const float* __restrict__ W,
                                                 const float* __restrict__ dinv,
                                                 _Float16* __restrict__ C, int nrows) {
  __shared__ float As[64 * K];
  const int t = threadIdx.x;
  const int lane = t & 63;
  const int wid = __builtin_amdgcn_readfirstlane(t >> 6);
  const int row0 = blockIdx.x * 64;

  constexpr int F4_PER_ROW = K / 4;
  constexpr int ROW_SHIFT = (K == 128) ? 5 : 4;
#pragma unroll
  for (int i = 0; i < K / 16; ++i) {
    int e4 = t + 256 * i;
    int r = e4 >> ROW_SHIFT;
    int k = (e4 & (F4_PER_ROW - 1)) * 4;
    int rc = row0 + r;
    if (rc > nrows - 1) rc = nrows - 1;
    float4 v = *(const float4*)(A + (size_t)rc * K + k);
    int s = r & 31;
    As[r * K + ((k + 0) ^ s)] = v.x;
    As[r * K + ((k + 1) ^ s)] = v.y;
    As[r * K + ((k + 2) ^ s)] = v.z;
    As[r * K + ((k + 3) ^ s)] = v.w;
  }
  __syncthreads();

  const int colbase = wid * 16;
  const float* Wc = W + colbase;
  float acc[16];
#pragma unroll
  for (int j = 0; j < 16; ++j) acc[j] = 0.0f;
  const int sw = lane & 31;
  const float* Arow = As + lane * K;

#pragma unroll 8
  for (int k = 0; k < K; ++k) {
    float a = Arow[k ^ sw];
    const float* Wk = Wc + k * 64;
#pragma unroll
    for (int j = 0; j < 16; ++j) acc[j] = fmaf(a, Wk[j], acc[j]);
  }

  int row = row0 + lane;
  if (row < nrows) {
    float dv = dinv[row];
    _Float16* Crow = C + (size_t)row * 64 + colbase;
    half8 o0, o1;
#pragma unroll
    for (int q = 0; q < 8; ++q) o0[q] = (_Float16)(dv * acc[q]);
#pragma unroll
    for (int q = 0; q < 8; ++q) o1[q] = (_Float16)(dv * acc[8 + q]);
    *(half8*)(Crow + 0) = o0;
    *(half8*)(Crow + 8) = o1;
  }
}

// --- agg v8: 4 edges per gather instruction ---------------------------------
// Wave handles 1 node. lane = (g,s): g=edge slot (0..3), s=feature quad.
// Each batch: 4 scalar idx loads (s_load; node uniform) + ONE vector gather
// (each lane 8B = 4 fp16 of its slot's row). Butterfly over g at the end.
__global__ __launch_bounds__(256) void agg_kernel(const _Float16* __restrict__ hp,
                                                  const int* __restrict__ rowptr,
                                                  const int* __restrict__ csr_src,
                                                  const float* __restrict__ dinv,
                                                  const float* __restrict__ bias,
                                                  float* __restrict__ out, int n) {
  const int t = threadIdx.x;
  const int lane = t & 63;
  const int g = lane >> 4;
  const int s = lane & 15;
  const int wid = __builtin_amdgcn_readfirstlane(t >> 6);
  const int node = blockIdx.x * 4 + wid;   // wave-uniform
  if (node >= n) return;
  const int rbeg = rowptr[node];           // s_load
  const int rend = rowptr[node + 1];
  const int deg = rend - rbeg;
  const int nbf = deg >> 2;
  const int rem = deg & 3;

  float a0 = 0.0f, a1 = 0.0f, a2 = 0.0f, a3 = 0.0f;
  {  // self term: counted once (group 0 only)
    h4 v = *(const h4*)(hp + ((size_t)node << 6) + (s << 2));
    if (g == 0) { a0 += (float)v[0]; a1 += (float)v[1]; a2 += (float)v[2]; a3 += (float)v[3]; }
  }

  int j = rbeg;
#pragma unroll 2
  for (int b = 0; b < nbf; ++b, j += 4) {
    int i0 = csr_src[j + 0];  // scalar loads (uniform addr)
    int i1 = csr_src[j + 1];
    int i2 = csr_src[j + 2];
    int i3 = csr_src[j + 3];
    int idx = (g & 2) ? ((g & 1) ? i3 : i2) : ((g & 1) ? i1 : i0);
    h4 v = *(const h4*)(hp + ((size_t)idx << 6) + (s << 2));  // 1 gather / 4 edges
    a0 += (float)v[0];
    a1 += (float)v[1];
    a2 += (float)v[2];
    a3 += (float)v[3];
  }
  if (rem) {
    int i0 = csr_src[j + 0];
    int i1 = (rem > 1) ? csr_src[j + 1] : i0;
    int i2 = (rem > 2) ? csr_src[j + 2] : i0;
    int idx = (g & 2) ? i2 : ((g & 1) ? i1 : i0);
    h4 v = *(const h4*)(hp + ((size_t)idx << 6) + (s << 2));
    float w = (g < rem) ? 1.0f : 0.0f;
    a0 = fmaf(w, (float)v[0], a0);
    a1 = fmaf(w, (float)v[1], a1);
    a2 = fmaf(w, (float)v[2], a2);
    a3 = fmaf(w, (float)v[3], a3);
  }

  // reduce across the 4 edge-slot groups (lanes s, s+16, s+32, s+48)
  a0 += __shfl_xor(a0, 16); a0 += __shfl_xor(a0, 32);
  a1 += __shfl_xor(a1, 16); a1 += __shfl_xor(a1, 32);
  a2 += __shfl_xor(a2, 16); a2 += __shfl_xor(a2, 32);
  a3 += __shfl_xor(a3, 16); a3 += __shfl_xor(a3, 32);

  const float dv = dinv[node];
  float4 bb = *(const float4*)(bias + (s << 2));
  float4 r;
  r.x = fmaxf(fmaf(dv, a0, bb.x), 0.0f);
  r.y = fmaxf(fmaf(dv, a1, bb.y), 0.0f);
  r.z = fmaxf(fmaf(dv, a2, bb.z), 0.0f);
  r.w = fmaxf(fmaf(dv, a3, bb.w), 0.0f);
  if (g == 0) *(float4*)(out + ((size_t)node << 6) + (s << 2)) = r;
}

// --- pooling: per-feature sum and max over all nodes (fp32 input) -----------
__global__ __launch_bounds__(256) void pool_kernel(const float* __restrict__ gbuf,
                                                   float* __restrict__ psum,
                                                   unsigned int* __restrict__ pmax, int n) {
  __shared__ float ls[4][64];
  __shared__ float lm[4][64];
  int lane = threadIdx.x & 63;
  int wid = threadIdx.x >> 6;
  float s = 0.0f, m = 0.0f;  // post-relu values >= 0
  for (int node = blockIdx.x * 4 + wid; node < n; node += gridDim.x * 4) {
    float v = gbuf[((size_t)node << 6) + lane];
    s += v;
    m = fmaxf(m, v);
  }
  ls[wid][lane] = s;
  lm[wid][lane] = m;
  __syncthreads();
  if (wid == 0) {
    for (int w = 1; w < 4; ++w) {
      s += ls[w][lane];
      m = fmaxf(m, lm[w][lane]);
    }
    atomicAdd(&psum[lane], s);
    atomicMax(&pmax[lane], __float_as_uint(m));
  }
}

// --- MLP head ---------------------------------------------------------------
__global__ __launch_bounds__(64) void head_kernel(const float* __restrict__ psum,
                                                  const float* __restrict__ pmaxf,
                                                  const float* __restrict__ fw1,
                                                  const float* __restrict__ fb1,
                                                  const float* __restrict__ fw2,
                                                  const float* __restrict__ fb2,
                                                  float* __restrict__ out, float invN) {
  int lane = threadIdx.x;
  float acc = fb1[lane];
#pragma unroll 4
  for (int k = 0; k < 64; ++k)
    acc = fmaf(psum[k] * invN, fw1[k * 64 + lane], acc);
#pragma unroll 4
  for (int k = 0; k < 64; ++k)
    acc = fmaf(pmaxf[k], fw1[(64 + k) * 64 + lane], acc);
  float a = fmaxf(acc, 0.0f) * fw2[lane];
  for (int off = 32; off > 0; off >>= 1) a += __shfl_down(a, off);
  if (lane == 0) out[0] = a + fb2[0];
}

extern "C" void kernel_launch(void* const* d_in, const int* in_sizes, int n_in,
                              void* d_out, int out_size, void* d_ws, size_t ws_size,
                              hipStream_t stream) {
  const float* x   = (const float*)d_in[0];
  const int*   ei  = (const int*)d_in[1];
  const float* W1  = (const float*)d_in[2];
  const float* b1  = (const float*)d_in[3];
  const float* W2  = (const float*)d_in[4];
  const float* b2  = (const float*)d_in[5];
  const float* W3  = (const float*)d_in[6];
  const float* b3  = (const float*)d_in[7];
  const float* fw1 = (const float*)d_in[8];
  const float* fb1 = (const float*)d_in[9];
  const float* fw2 = (const float*)d_in[10];
  const float* fb2 = (const float*)d_in[11];
  float* out = (float*)d_out;

  const int N = in_sizes[0] / 128;  // 50000
  const int E = in_sizes[1] / 2;    // 800000
  const int* src = ei;
  const int* dst = ei + E;

  char* ws = (char*)d_ws;
  size_t off = 0;
  auto alloc = [&](size_t bytes) -> char* {
    char* p = ws + off;
    off = (off + bytes + 255) & ~(size_t)255;
    return p;
  };
  float*        dinv    = (float*)alloc((size_t)N * 4);
  int*          degc    = (int*)alloc((size_t)N * 4);
  int*          rowptr  = (int*)alloc((size_t)(N + 1) * 4);
  int*          bsum    = (int*)alloc(256 * 4);
  int*          bkt_cur = (int*)alloc(256 * 4);
  int*          binned  = (int*)alloc((size_t)E * 4 + 64);
  int*          csr_src = (int*)alloc((size_t)E * 4 + 64);  // pad: safe overread
  _Float16*     bufA    = (_Float16*)alloc((size_t)N * 64 * 2);
  float*        bufB    = (float*)alloc((size_t)N * 64 * 4);
  float*        psum    = (float*)alloc(64 * 4);
  unsigned int* pmax    = (unsigned int*)alloc(64 * 4);

  const int histBlk = (E + 255) / 256;
  const int scanBlk = (N + 255) / 256;   // 196 (<=256, required by scanB)
  const int mmBlk   = (N + 63) / 64;
  const int aggBlk  = (N + 3) / 4;       // 1 node per wave
  const int NB      = (N + 255) / 256;   // 196 buckets
  const int binBlk  = (E + 4095) / 4096; // 196 tiles

  zero_kernel<<<scanBlk, 256, 0, stream>>>(degc, psum, pmax, N);
  hist_kernel<<<histBlk, 256, 0, stream>>>(dst, degc, E);
  scanA_kernel<<<scanBlk, 256, 0, stream>>>(degc, bsum, N);
  scanB_kernel<<<1, 256, 0, stream>>>(bsum, scanBlk);
  scanC_kernel<<<scanBlk, 256, 0, stream>>>(degc, bsum, rowptr, dinv, bkt_cur, N, E);
  binA_kernel<<<binBlk, 256, 0, stream>>>(src, dst, bkt_cur, binned, E);
  binB_kernel<<<NB, 256, 0, stream>>>(rowptr, binned, csr_src, N);

  // layer 1
  mm_kernel<128><<<mmBlk, 256, 0, stream>>>(x, W1, dinv, bufA, N);
  agg_kernel<<<aggBlk, 256, 0, stream>>>(bufA, rowptr, csr_src, dinv, b1, bufB, N);
  // layer 2
  mm_kernel<64><<<mmBlk, 256, 0, stream>>>(bufB, W2, dinv, bufA, N);
  agg_kernel<<<aggBlk, 256, 0, stream>>>(bufA, rowptr, csr_src, dinv, b2, bufB, N);
  // layer 3
  mm_kernel<64><<<mmBlk, 256, 0, stream>>>(bufB, W3, dinv, bufA, N);
  agg_kernel<<<aggBlk, 256, 0, stream>>>(bufA, rowptr, csr_src, dinv, b3, bufB, N);

  pool_kernel<<<2048, 256, 0, stream>>>(bufB, psum, pmax, N);
  head_kernel<<<1, 64, 0, stream>>>(psum, (const float*)pmax, fw1, fb1, fw2, fb2, out,
                                    1.0f / (float)N);
}

// Round 9
// 300.329 us; speedup vs baseline: 1.2194x; 1.1195x over previous
//
#include <hip/hip_runtime.h>
#include <math.h>

// ---------------------------------------------------------------------------
// GCN critic network. v9 = v8 + pool atomic-depth fix.
// r8 counters: pool at 2048 blocks = 2048 serialized same-address RMWs
// (~25ns each = 52us, HBM 1.7%, VALU 1.5%). Also explains r3's fused
// agg_pool regression. Fix: 256 blocks (atomic depth 256 ~= 6us) + unroll-4
// independent node loads per wave to keep streaming parallelism.
// ---------------------------------------------------------------------------

typedef _Float16 h4 __attribute__((ext_vector_type(4)));
typedef _Float16 half8 __attribute__((ext_vector_type(8)));

__global__ __launch_bounds__(256) void zero_kernel(int* __restrict__ degc,
                                                   float* __restrict__ psum,
                                                   unsigned int* __restrict__ pmax, int n) {
  int i = blockIdx.x * 256 + threadIdx.x;
  if (i < n) degc[i] = 0;
  if (blockIdx.x == 0 && threadIdx.x < 64) {
    psum[threadIdx.x] = 0.0f;
    pmax[threadIdx.x] = 0u;
  }
}

__global__ __launch_bounds__(256) void hist_kernel(const int* __restrict__ dst,
                                                   int* __restrict__ degc, int E) {
  int e = blockIdx.x * 256 + threadIdx.x;
  if (e < E) atomicAdd(&degc[dst[e]], 1);
}

// --- hierarchical exclusive scan of degc -> rowptr --------------------------
__global__ __launch_bounds__(256) void scanA_kernel(const int* __restrict__ deg,
                                                    int* __restrict__ bsum, int n) {
  __shared__ int sdata[256];
  int t = threadIdx.x;
  int i = blockIdx.x * 256 + t;
  sdata[t] = (i < n) ? deg[i] : 0;
  __syncthreads();
  for (int off = 128; off > 0; off >>= 1) {
    if (t < off) sdata[t] += sdata[t + off];
    __syncthreads();
  }
  if (t == 0) bsum[blockIdx.x] = sdata[0];
}

__global__ __launch_bounds__(256) void scanB_kernel(int* __restrict__ bsum, int nb) {
  __shared__ int s[256];
  int t = threadIdx.x;
  int v = (t < nb) ? bsum[t] : 0;
  s[t] = v;
  __syncthreads();
  for (int off = 1; off < 256; off <<= 1) {
    int x = (t >= off) ? s[t - off] : 0;
    __syncthreads();
    s[t] += x;
    __syncthreads();
  }
  if (t < nb) bsum[t] = s[t] - v;  // exclusive block offsets
}

// scanC: rowptr + dinv + per-bucket write cursors (bucket = node>>8)
__global__ __launch_bounds__(256) void scanC_kernel(const int* __restrict__ deg,
                                                    const int* __restrict__ bsum,
                                                    int* __restrict__ rowptr,
                                                    float* __restrict__ dinv,
                                                    int* __restrict__ bkt_cur,
                                                    int n, int e_total) {
  __shared__ int s[256];
  int t = threadIdx.x;
  int i = blockIdx.x * 256 + t;
  int v = (i < n) ? deg[i] : 0;
  s[t] = v;
  __syncthreads();
  for (int off = 1; off < 256; off <<= 1) {
    int x = (t >= off) ? s[t - off] : 0;
    __syncthreads();
    s[t] += x;
    __syncthreads();
  }
  if (i < n) {
    int excl = bsum[blockIdx.x] + s[t] - v;
    rowptr[i] = excl;
    dinv[i] = 1.0f / sqrtf((float)v + 1.0f);
    if ((i & 255) == 0) bkt_cur[i >> 8] = excl;  // bucket base in CSR coords
  }
  if (i == 0) rowptr[n] = e_total;
}

// --- binA: bucket-sort edges by dst>>8, packed (src<<8)|(dst&255) -----------
__global__ __launch_bounds__(256) void binA_kernel(const int* __restrict__ src,
                                                   const int* __restrict__ dst,
                                                   int* __restrict__ bkt_cur,
                                                   int* __restrict__ binned, int E) {
  __shared__ int hist[256];
  __shared__ int scan[256];
  __shared__ int delta[256];
  __shared__ int lcur[256];
  __shared__ int sorted[4096];
  __shared__ unsigned char bkt_of[4096];
  const int t = threadIdx.x;
  hist[t] = 0;
  __syncthreads();
  const int e0 = blockIdx.x * 4096;
  int pk[16];
  int bk[16];
#pragma unroll
  for (int i = 0; i < 16; ++i) {
    int e = e0 + t + 256 * i;  // coalesced
    if (e < E) {
      int s_ = src[e], d_ = dst[e];
      int b = d_ >> 8;
      pk[i] = (s_ << 8) | (d_ & 255);
      bk[i] = b;
      atomicAdd(&hist[b], 1);
    } else {
      bk[i] = -1;
    }
  }
  __syncthreads();
  int v = hist[t];
  scan[t] = v;
  __syncthreads();
  for (int off = 1; off < 256; off <<= 1) {
    int x = (t >= off) ? scan[t - off] : 0;
    __syncthreads();
    scan[t] += x;
    __syncthreads();
  }
  int excl = scan[t] - v;
  int g = (v > 0) ? atomicAdd(&bkt_cur[t], v) : 0;  // reserve global space
  delta[t] = g - excl;
  lcur[t] = excl;
  __syncthreads();
#pragma unroll
  for (int i = 0; i < 16; ++i) {
    if (bk[i] >= 0) {
      int p = atomicAdd(&lcur[bk[i]], 1);
      sorted[p] = pk[i];
      bkt_of[p] = (unsigned char)bk[i];
    }
  }
  __syncthreads();
  const int tot = scan[255];
  for (int i = t; i < tot; i += 256)  // coalesced run writes
    binned[delta[bkt_of[i]] + i] = sorted[i];
}

// --- binB: per-bucket CSR build (one block per 256-node bucket) -------------
__global__ __launch_bounds__(256) void binB_kernel(const int* __restrict__ rowptr,
                                                   const int* __restrict__ binned,
                                                   int* __restrict__ csr_src, int n) {
  __shared__ int lcur[256];
  const int t = threadIdx.x;
  const int base = blockIdx.x << 8;
  const int rbeg = rowptr[base];
  const int node = base + t;
  lcur[t] = (node < n) ? rowptr[node] - rbeg : 0;
  const int nend = (base + 256 < n) ? base + 256 : n;
  const int rend = rowptr[nend];
  const int cnt = rend - rbeg;
  __syncthreads();
  for (int i = t; i < cnt; i += 256) {
    int e = binned[rbeg + i];               // coalesced read
    int p = atomicAdd(&lcur[e & 255], 1);   // LDS cursor
    csr_src[rbeg + p] = e >> 8;             // scatter within 16KB window
  }
}

// --- dense matmul C[N,64] = fp16( dinv[row] * (A[N,K] @ W[K,64]) ) ----------
template <int K>
__global__ __launch_bounds__(256) void mm_kernel(const float* __restrict__ A,
                                                 const float* __restrict__ W,
                                                 const float* __restrict__ dinv,
                                                 _Float16* __restrict__ C, int nrows) {
  __shared__ float As[64 * K];
  const int t = threadIdx.x;
  const int lane = t & 63;
  const int wid = __builtin_amdgcn_readfirstlane(t >> 6);
  const int row0 = blockIdx.x * 64;

  constexpr int F4_PER_ROW = K / 4;
  constexpr int ROW_SHIFT = (K == 128) ? 5 : 4;
#pragma unroll
  for (int i = 0; i < K / 16; ++i) {
    int e4 = t + 256 * i;
    int r = e4 >> ROW_SHIFT;
    int k = (e4 & (F4_PER_ROW - 1)) * 4;
    int rc = row0 + r;
    if (rc > nrows - 1) rc = nrows - 1;
    float4 v = *(const float4*)(A + (size_t)rc * K + k);
    int s = r & 31;
    As[r * K + ((k + 0) ^ s)] = v.x;
    As[r * K + ((k + 1) ^ s)] = v.y;
    As[r * K + ((k + 2) ^ s)] = v.z;
    As[r * K + ((k + 3) ^ s)] = v.w;
  }
  __syncthreads();

  const int colbase = wid * 16;
  const float* Wc = W + colbase;
  float acc[16];
#pragma unroll
  for (int j = 0; j < 16; ++j) acc[j] = 0.0f;
  const int sw = lane & 31;
  const float* Arow = As + lane * K;

#pragma unroll 8
  for (int k = 0; k < K; ++k) {
    float a = Arow[k ^ sw];
    const float* Wk = Wc + k * 64;
#pragma unroll
    for (int j = 0; j < 16; ++j) acc[j] = fmaf(a, Wk[j], acc[j]);
  }

  int row = row0 + lane;
  if (row < nrows) {
    float dv = dinv[row];
    _Float16* Crow = C + (size_t)row * 64 + colbase;
    half8 o0, o1;
#pragma unroll
    for (int q = 0; q < 8; ++q) o0[q] = (_Float16)(dv * acc[q]);
#pragma unroll
    for (int q = 0; q < 8; ++q) o1[q] = (_Float16)(dv * acc[8 + q]);
    *(half8*)(Crow + 0) = o0;
    *(half8*)(Crow + 8) = o1;
  }
}

// --- agg v8: 4 edges per gather instruction ---------------------------------
__global__ __launch_bounds__(256) void agg_kernel(const _Float16* __restrict__ hp,
                                                  const int* __restrict__ rowptr,
                                                  const int* __restrict__ csr_src,
                                                  const float* __restrict__ dinv,
                                                  const float* __restrict__ bias,
                                                  float* __restrict__ out, int n) {
  const int t = threadIdx.x;
  const int lane = t & 63;
  const int g = lane >> 4;
  const int s = lane & 15;
  const int wid = __builtin_amdgcn_readfirstlane(t >> 6);
  const int node = blockIdx.x * 4 + wid;   // wave-uniform
  if (node >= n) return;
  const int rbeg = rowptr[node];           // s_load
  const int rend = rowptr[node + 1];
  const int deg = rend - rbeg;
  const int nbf = deg >> 2;
  const int rem = deg & 3;

  float a0 = 0.0f, a1 = 0.0f, a2 = 0.0f, a3 = 0.0f;
  {  // self term: counted once (group 0 only)
    h4 v = *(const h4*)(hp + ((size_t)node << 6) + (s << 2));
    if (g == 0) { a0 += (float)v[0]; a1 += (float)v[1]; a2 += (float)v[2]; a3 += (float)v[3]; }
  }

  int j = rbeg;
#pragma unroll 2
  for (int b = 0; b < nbf; ++b, j += 4) {
    int i0 = csr_src[j + 0];  // scalar loads (uniform addr)
    int i1 = csr_src[j + 1];
    int i2 = csr_src[j + 2];
    int i3 = csr_src[j + 3];
    int idx = (g & 2) ? ((g & 1) ? i3 : i2) : ((g & 1) ? i1 : i0);
    h4 v = *(const h4*)(hp + ((size_t)idx << 6) + (s << 2));  // 1 gather / 4 edges
    a0 += (float)v[0];
    a1 += (float)v[1];
    a2 += (float)v[2];
    a3 += (float)v[3];
  }
  if (rem) {
    int i0 = csr_src[j + 0];
    int i1 = (rem > 1) ? csr_src[j + 1] : i0;
    int i2 = (rem > 2) ? csr_src[j + 2] : i0;
    int idx = (g & 2) ? i2 : ((g & 1) ? i1 : i0);
    h4 v = *(const h4*)(hp + ((size_t)idx << 6) + (s << 2));
    float w = (g < rem) ? 1.0f : 0.0f;
    a0 = fmaf(w, (float)v[0], a0);
    a1 = fmaf(w, (float)v[1], a1);
    a2 = fmaf(w, (float)v[2], a2);
    a3 = fmaf(w, (float)v[3], a3);
  }

  // reduce across the 4 edge-slot groups (lanes s, s+16, s+32, s+48)
  a0 += __shfl_xor(a0, 16); a0 += __shfl_xor(a0, 32);
  a1 += __shfl_xor(a1, 16); a1 += __shfl_xor(a1, 32);
  a2 += __shfl_xor(a2, 16); a2 += __shfl_xor(a2, 32);
  a3 += __shfl_xor(a3, 16); a3 += __shfl_xor(a3, 32);

  const float dv = dinv[node];
  float4 bb = *(const float4*)(bias + (s << 2));
  float4 r;
  r.x = fmaxf(fmaf(dv, a0, bb.x), 0.0f);
  r.y = fmaxf(fmaf(dv, a1, bb.y), 0.0f);
  r.z = fmaxf(fmaf(dv, a2, bb.z), 0.0f);
  r.w = fmaxf(fmaf(dv, a3, bb.w), 0.0f);
  if (g == 0) *(float4*)(out + ((size_t)node << 6) + (s << 2)) = r;
}

// --- pooling: 256 blocks (atomic depth 256), unroll-4 independent loads -----
__global__ __launch_bounds__(256) void pool_kernel(const float* __restrict__ gbuf,
                                                   float* __restrict__ psum,
                                                   unsigned int* __restrict__ pmax, int n) {
  __shared__ float ls[4][64];
  __shared__ float lm[4][64];
  const int lane = threadIdx.x & 63;
  const int wid = threadIdx.x >> 6;
  const int stride = 256 * 4;  // wave-slots
  float s = 0.0f, m = 0.0f;    // post-relu values >= 0
  for (int base = blockIdx.x * 4 + wid; base < n; base += 4 * stride) {
#pragma unroll
    for (int k = 0; k < 4; ++k) {  // 4 independent loads in flight
      int node = base + k * stride;
      if (node < n) {
        float v = gbuf[((size_t)node << 6) + lane];
        s += v;
        m = fmaxf(m, v);
      }
    }
  }
  ls[wid][lane] = s;
  lm[wid][lane] = m;
  __syncthreads();
  if (wid == 0) {
    for (int w = 1; w < 4; ++w) {
      s += ls[w][lane];
      m = fmaxf(m, lm[w][lane]);
    }
    atomicAdd(&psum[lane], s);
    atomicMax(&pmax[lane], __float_as_uint(m));
  }
}

// --- MLP head ---------------------------------------------------------------
__global__ __launch_bounds__(64) void head_kernel(const float* __restrict__ psum,
                                                  const float* __restrict__ pmaxf,
                                                  const float* __restrict__ fw1,
                                                  const float* __restrict__ fb1,
                                                  const float* __restrict__ fw2,
                                                  const float* __restrict__ fb2,
                                                  float* __restrict__ out, float invN) {
  int lane = threadIdx.x;
  float acc = fb1[lane];
#pragma unroll 4
  for (int k = 0; k < 64; ++k)
    acc = fmaf(psum[k] * invN, fw1[k * 64 + lane], acc);
#pragma unroll 4
  for (int k = 0; k < 64; ++k)
    acc = fmaf(pmaxf[k], fw1[(64 + k) * 64 + lane], acc);
  float a = fmaxf(acc, 0.0f) * fw2[lane];
  for (int off = 32; off > 0; off >>= 1) a += __shfl_down(a, off);
  if (lane == 0) out[0] = a + fb2[0];
}

extern "C" void kernel_launch(void* const* d_in, const int* in_sizes, int n_in,
                              void* d_out, int out_size, void* d_ws, size_t ws_size,
                              hipStream_t stream) {
  const float* x   = (const float*)d_in[0];
  const int*   ei  = (const int*)d_in[1];
  const float* W1  = (const float*)d_in[2];
  const float* b1  = (const float*)d_in[3];
  const float* W2  = (const float*)d_in[4];
  const float* b2  = (const float*)d_in[5];
  const float* W3  = (const float*)d_in[6];
  const float* b3  = (const float*)d_in[7];
  const float* fw1 = (const float*)d_in[8];
  const float* fb1 = (const float*)d_in[9];
  const float* fw2 = (const float*)d_in[10];
  const float* fb2 = (const float*)d_in[11];
  float* out = (float*)d_out;

  const int N = in_sizes[0] / 128;  // 50000
  const int E = in_sizes[1] / 2;    // 800000
  const int* src = ei;
  const int* dst = ei + E;

  char* ws = (char*)d_ws;
  size_t off = 0;
  auto alloc = [&](size_t bytes) -> char* {
    char* p = ws + off;
    off = (off + bytes + 255) & ~(size_t)255;
    return p;
  };
  float*        dinv    = (float*)alloc((size_t)N * 4);
  int*          degc    = (int*)alloc((size_t)N * 4);
  int*          rowptr  = (int*)alloc((size_t)(N + 1) * 4);
  int*          bsum    = (int*)alloc(256 * 4);
  int*          bkt_cur = (int*)alloc(256 * 4);
  int*          binned  = (int*)alloc((size_t)E * 4 + 64);
  int*          csr_src = (int*)alloc((size_t)E * 4 + 64);  // pad: safe overread
  _Float16*     bufA    = (_Float16*)alloc((size_t)N * 64 * 2);
  float*        bufB    = (float*)alloc((size_t)N * 64 * 4);
  float*        psum    = (float*)alloc(64 * 4);
  unsigned int* pmax    = (unsigned int*)alloc(64 * 4);

  const int histBlk = (E + 255) / 256;
  const int scanBlk = (N + 255) / 256;   // 196 (<=256, required by scanB)
  const int mmBlk   = (N + 63) / 64;
  const int aggBlk  = (N + 3) / 4;       // 1 node per wave
  const int NB      = (N + 255) / 256;   // 196 buckets
  const int binBlk  = (E + 4095) / 4096; // 196 tiles

  zero_kernel<<<scanBlk, 256, 0, stream>>>(degc, psum, pmax, N);
  hist_kernel<<<histBlk, 256, 0, stream>>>(dst, degc, E);
  scanA_kernel<<<scanBlk, 256, 0, stream>>>(degc, bsum, N);
  scanB_kernel<<<1, 256, 0, stream>>>(bsum, scanBlk);
  scanC_kernel<<<scanBlk, 256, 0, stream>>>(degc, bsum, rowptr, dinv, bkt_cur, N, E);
  binA_kernel<<<binBlk, 256, 0, stream>>>(src, dst, bkt_cur, binned, E);
  binB_kernel<<<NB, 256, 0, stream>>>(rowptr, binned, csr_src, N);

  // layer 1
  mm_kernel<128><<<mmBlk, 256, 0, stream>>>(x, W1, dinv, bufA, N);
  agg_kernel<<<aggBlk, 256, 0, stream>>>(bufA, rowptr, csr_src, dinv, b1, bufB, N);
  // layer 2
  mm_kernel<64><<<mmBlk, 256, 0, stream>>>(bufB, W2, dinv, bufA, N);
  agg_kernel<<<aggBlk, 256, 0, stream>>>(bufA, rowptr, csr_src, dinv, b2, bufB, N);
  // layer 3
  mm_kernel<64><<<mmBlk, 256, 0, stream>>>(bufB, W3, dinv, bufA, N);
  agg_kernel<<<aggBlk, 256, 0, stream>>>(bufA, rowptr, csr_src, dinv, b3, bufB, N);

  pool_kernel<<<256, 256, 0, stream>>>(bufB, psum, pmax, N);
  head_kernel<<<1, 64, 0, stream>>>(psum, (const float*)pmax, fw1, fb1, fw2, fb2, out,
                                    1.0f / (float)N);
}